// Round 4
// baseline (54.660 us; speedup 1.0000x reference)
//
#include <hip/hip_runtime.h>

// 256 independent MLPs (2->32->2), 16384 rows. VALU-bound, issue stream is
// near the arithmetic floor (~12 reg + 1 trans per element). Round 4: fix the
// grid-capped occupancy (was 4 blocks/CU = 50%): TPB 256->128, CPB=8 ->
// 4096 blocks = 16 blocks/CU = 32 waves/CU. Writeback segments stay 64B.

typedef float f32x2 __attribute__((ext_vector_type(2)));

#define NCH   256
#define HID   32
#define BATCH 16384
#define TPB   128   // threads per block = batch rows per block
#define CPB   8     // channels per block

static __device__ __forceinline__ f32x2 vabs(f32x2 v) {
    f32x2 r; r.x = __builtin_fabsf(v.x); r.y = __builtin_fabsf(v.y); return r;
}

__global__ __launch_bounds__(TPB, 8) void fused_mlp_kernel(
    const float* __restrict__ x,    // [BATCH,2]
    const float* __restrict__ W0,   // [NCH,HID,2]
    const float* __restrict__ b0,   // [NCH,HID]
    const float* __restrict__ W1,   // [NCH,2,HID]
    const float* __restrict__ b1,   // [NCH,2]
    float* __restrict__ out)        // [BATCH,NCH,2]
{
    // A&S 7.1.27: erf(u) ~ 1 - 1/(1+a1 u+a2 u^2+a3 u^3+a4 u^4)^4, u>=0, |eps|<=5e-4
    // u = |x|/sqrt(2) folded into coefficients (poly in |x| directly).
    const f32x2 A1 = {0.19685390f, 0.19685390f};     // 0.278393/sqrt2
    const f32x2 A2 = {0.11519450f, 0.11519450f};     // 0.230389/2
    const f32x2 A3 = {3.4365516e-4f, 3.4365516e-4f}; // 0.000972/(2 sqrt2)
    const f32x2 A4 = {0.019527f, 0.019527f};         // 0.078108/4

    __shared__ f32x2 tile[TPB][CPB + 1];   // (out0,out1) per (row, channel); pad row

    const int tid  = threadIdx.x;
    const int nbb  = BATCH / TPB;          // 128 batch blocks
    const int bblk = blockIdx.x % nbb;
    const int cblk = blockIdx.x / nbb;
    const int b    = bblk * TPB + tid;
    const int c0   = cblk * CPB;

    const float2 xv = *reinterpret_cast<const float2*>(x + (size_t)b * 2);
    const f32x2 x0v = {xv.x, xv.x};
    const f32x2 x1v = {xv.y, xv.y};

    for (int cl = 0; cl < CPB; ++cl) {
        const int c = c0 + cl;             // wave-uniform -> scalar weight loads
        const float* __restrict__ w0 = W0 + (size_t)c * (HID * 2);
        const float* __restrict__ bb = b0 + (size_t)c * HID;
        const float* __restrict__ w1 = W1 + (size_t)c * (2 * HID);

        f32x2 acc0 = {0.0f, 0.0f};         // accumulate q = 2*gelu; halve at end
        f32x2 acc1 = {0.0f, 0.0f};

        #pragma unroll
        for (int h4 = 0; h4 < HID / 4; ++h4) {     // 2 packed pairs per iter
            f32x2 pre[2], ax[2], p4[2];
            #pragma unroll
            for (int j = 0; j < 2; ++j) {
                const int hp = h4 * 2 + j;
                const f32x2 w0a = {w0[4*hp + 0], w0[4*hp + 2]};
                const f32x2 w0b = {w0[4*hp + 1], w0[4*hp + 3]};
                const f32x2 bbp = {bb[2*hp + 0], bb[2*hp + 1]};
                pre[j] = x0v * w0a + (x1v * w0b + bbp);
                ax[j]  = vabs(pre[j]);
                f32x2 t = A4 * ax[j] + A3;
                t = t * ax[j] + A2;
                t = t * ax[j] + A1;
                f32x2 P = t * ax[j] + f32x2{1.0f, 1.0f};
                f32x2 P2 = P * P;
                p4[j] = P2 * P2;
            }
            // shared rcp per pair: inv = 1/P^4 elementwise
            const float m0 = p4[0].x * p4[0].y;
            const float m1 = p4[1].x * p4[1].y;
            const float R0 = __builtin_amdgcn_rcpf(m0);
            const float R1 = __builtin_amdgcn_rcpf(m1);
            const f32x2 inv0 = {R0 * p4[0].y, R0 * p4[0].x};
            const f32x2 inv1 = {R1 * p4[1].y, R1 * p4[1].x};
            // q = 2*gelu = (x + |x|) - |x| * inv   (exact limits: ->2x, ->0)
            const f32x2 q0 = (pre[0] + ax[0]) - ax[0] * inv0;
            const f32x2 q1 = (pre[1] + ax[1]) - ax[1] * inv1;

            {
                const int hp = h4 * 2;
                const f32x2 w1a = {w1[2*hp + 0], w1[2*hp + 1]};
                const f32x2 w1b = {w1[HID + 2*hp + 0], w1[HID + 2*hp + 1]};
                acc0 = acc0 + q0 * w1a;
                acc1 = acc1 + q0 * w1b;
            }
            {
                const int hp = h4 * 2 + 1;
                const f32x2 w1a = {w1[2*hp + 0], w1[2*hp + 1]};
                const f32x2 w1b = {w1[HID + 2*hp + 0], w1[HID + 2*hp + 1]};
                acc0 = acc0 + q1 * w1a;
                acc1 = acc1 + q1 * w1b;
            }
        }

        const float r0 = 0.5f * (acc0.x + acc0.y) + b1[2*c + 0];
        const float r1 = 0.5f * (acc1.x + acc1.y) + b1[2*c + 1];
        tile[tid][cl] = f32x2{r0, r1};
    }

    __syncthreads();

    // Coalesced writeback: out as f32x2 array [BATCH][NCH]; 64B segments/row
    f32x2* __restrict__ out2 = reinterpret_cast<f32x2*>(out);
    const size_t obase = (size_t)bblk * TPB * NCH + c0;
    #pragma unroll
    for (int i = 0; i < CPB; ++i) {
        int flat = i * TPB + tid;
        int bl   = flat >> 3;      // / CPB
        int jp   = flat & (CPB - 1);
        out2[obase + (size_t)bl * NCH + jp] = tile[bl][jp];
    }
}

extern "C" void kernel_launch(void* const* d_in, const int* in_sizes, int n_in,
                              void* d_out, int out_size, void* d_ws, size_t ws_size,
                              hipStream_t stream) {
    const float* x  = (const float*)d_in[0];
    const float* W0 = (const float*)d_in[1];
    const float* b0 = (const float*)d_in[2];
    const float* W1 = (const float*)d_in[3];
    const float* b1 = (const float*)d_in[4];
    float* out = (float*)d_out;

    dim3 grid((BATCH / TPB) * (NCH / CPB));
    dim3 block(TPB);
    fused_mlp_kernel<<<grid, block, 0, stream>>>(x, W0, b0, W1, b1, out);
}

// Round 5
// 48.036 us; speedup vs baseline: 1.1379x; 1.1379x over previous
//
#include <hip/hip_runtime.h>

// 256 independent MLPs (2->32->2), 16384 rows. VALU-bound.
// Round 5: pack f32x2 over BATCH-ROW PAIRS (not h-pairs) so every weight is a
// scalar splat (no 2-SGPR vector assembly), amortized over ROWS=4 rows via two
// independent pk chains. TPB=64, LDS [4][64][9] transpose for coalesced writes.

typedef float f32x2 __attribute__((ext_vector_type(2)));

#define NCH   256
#define HID   32
#define BATCH 16384
#define TPB   64    // one wave per block
#define CPB   8     // channels per block
#define ROWS  4     // batch rows per thread = 2 pk chains

static __device__ __forceinline__ f32x2 vabs2(f32x2 v) {
    f32x2 r; r.x = __builtin_fabsf(v.x); r.y = __builtin_fabsf(v.y); return r;
}

__global__ __launch_bounds__(TPB, 4) void fused_mlp_kernel(
    const float* __restrict__ x,    // [BATCH,2]
    const float* __restrict__ W0,   // [NCH,HID,2]
    const float* __restrict__ b0,   // [NCH,HID]
    const float* __restrict__ W1,   // [NCH,2,HID]
    const float* __restrict__ b1,   // [NCH,2]
    float* __restrict__ out)        // [BATCH,NCH,2]
{
    // A&S 7.1.27 erf poly, sqrt(2) folded (|eps|<=5e-4); q = 2*gelu.
    const f32x2 A1 = {0.19685390f, 0.19685390f};
    const f32x2 A2 = {0.11519450f, 0.11519450f};
    const f32x2 A3 = {3.4365516e-4f, 3.4365516e-4f};
    const f32x2 A4 = {0.019527f, 0.019527f};
    const f32x2 ONE = {1.0f, 1.0f};

    __shared__ f32x2 tile[ROWS][TPB][CPB + 1];   // 18432 B

    const int tid   = threadIdx.x;
    const int nbb   = BATCH / (TPB * ROWS);      // 64
    const int bblk  = blockIdx.x % nbb;
    const int cblk  = blockIdx.x / nbb;
    const int c0    = cblk * CPB;
    const int rbase = bblk * (TPB * ROWS);

    float2 xr[ROWS];
    #pragma unroll
    for (int k = 0; k < ROWS; ++k)
        xr[k] = *reinterpret_cast<const float2*>(x + (size_t)(rbase + k * TPB + tid) * 2);
    // chain A = rows k0,k1 ; chain B = rows k2,k3
    const f32x2 xA0 = {xr[0].x, xr[1].x}, xA1 = {xr[0].y, xr[1].y};
    const f32x2 xB0 = {xr[2].x, xr[3].x}, xB1 = {xr[2].y, xr[3].y};

    for (int cl = 0; cl < CPB; ++cl) {
        const int c = c0 + cl;                   // wave-uniform
        const float* __restrict__ w0 = W0 + (size_t)c * (HID * 2);
        const float* __restrict__ bb = b0 + (size_t)c * HID;
        const float* __restrict__ w1 = W1 + (size_t)c * (2 * HID);

        f32x2 aA0 = {0,0}, aA1 = {0,0}, aB0 = {0,0}, aB1 = {0,0};

        #pragma unroll
        for (int h = 0; h < HID; ++h) {
            const float s_wa = w0[2*h], s_wb = w0[2*h+1], s_bh = bb[h];
            const f32x2 wa = {s_wa, s_wa}, wb = {s_wb, s_wb}, bh = {s_bh, s_bh};

            f32x2 preA = xA0 * wa + (xA1 * wb + bh);
            f32x2 preB = xB0 * wa + (xB1 * wb + bh);
            f32x2 axA = vabs2(preA), axB = vabs2(preB);

            f32x2 tA = A4 * axA + A3; tA = tA * axA + A2; tA = tA * axA + A1;
            f32x2 PA = tA * axA + ONE;
            f32x2 tB = A4 * axB + A3; tB = tB * axB + A2; tB = tB * axB + A1;
            f32x2 PB = tB * axB + ONE;

            f32x2 P2A = PA * PA, P4A = P2A * P2A;
            f32x2 P2B = PB * PB, P4B = P2B * P2B;

            const float mA = P4A.x * P4A.y;
            const float mB = P4B.x * P4B.y;
            const float RA = __builtin_amdgcn_rcpf(mA);
            const float RB = __builtin_amdgcn_rcpf(mB);
            const f32x2 invA = {RA * P4A.y, RA * P4A.x};
            const f32x2 invB = {RB * P4B.y, RB * P4B.x};

            // q = 2*gelu = (x + |x|) - |x|/P^4
            f32x2 qA = (preA + axA) - axA * invA;
            f32x2 qB = (preB + axB) - axB * invB;

            const float s_w1a = w1[h], s_w1b = w1[HID + h];
            const f32x2 w1a = {s_w1a, s_w1a}, w1b = {s_w1b, s_w1b};
            aA0 = aA0 + qA * w1a;  aA1 = aA1 + qA * w1b;
            aB0 = aB0 + qB * w1a;  aB1 = aB1 + qB * w1b;
        }

        const float bo0 = b1[2*c], bo1 = b1[2*c + 1];
        tile[0][tid][cl] = f32x2{0.5f * aA0.x + bo0, 0.5f * aA1.x + bo1};
        tile[1][tid][cl] = f32x2{0.5f * aA0.y + bo0, 0.5f * aA1.y + bo1};
        tile[2][tid][cl] = f32x2{0.5f * aB0.x + bo0, 0.5f * aB1.x + bo1};
        tile[3][tid][cl] = f32x2{0.5f * aB0.y + bo0, 0.5f * aB1.y + bo1};
    }

    __syncthreads();

    // Coalesced writeback: out as f32x2 [BATCH][NCH]; 64B segments per 8 lanes.
    f32x2* __restrict__ out2 = reinterpret_cast<f32x2*>(out);
    #pragma unroll
    for (int k = 0; k < ROWS; ++k) {
        const size_t obase = (size_t)(rbase + k * TPB) * NCH + c0;
        #pragma unroll
        for (int i = 0; i < CPB; ++i) {
            int flat = i * TPB + tid;
            int bl   = flat >> 3;        // / CPB
            int jp   = flat & (CPB - 1);
            out2[obase + (size_t)bl * NCH + jp] = tile[k][bl][jp];
        }
    }
}

extern "C" void kernel_launch(void* const* d_in, const int* in_sizes, int n_in,
                              void* d_out, int out_size, void* d_ws, size_t ws_size,
                              hipStream_t stream) {
    const float* x  = (const float*)d_in[0];
    const float* W0 = (const float*)d_in[1];
    const float* b0 = (const float*)d_in[2];
    const float* W1 = (const float*)d_in[3];
    const float* b1 = (const float*)d_in[4];
    float* out = (float*)d_out;

    dim3 grid((BATCH / (TPB * ROWS)) * (NCH / CPB));   // 64 * 32 = 2048
    dim3 block(TPB);
    fused_mlp_kernel<<<grid, block, 0, stream>>>(x, W0, b0, W1, b1, out);
}